// Round 10
// baseline (45.599 us; speedup 1.0000x reference)
//
#include <hip/hip_runtime.h>
#include <hip/hip_bf16.h>
#include <stdint.h>

#define DEVI __device__ __forceinline__

typedef __attribute__((ext_vector_type(8))) short short8;
typedef __attribute__((ext_vector_type(16))) float f32x16;
typedef __attribute__((ext_vector_type(4))) float f32x4;
typedef __attribute__((ext_vector_type(2))) unsigned int uint2v;
typedef unsigned short ushortT;

union U8 { short8 s8; unsigned u[4]; };

DEVI unsigned short f2bf(float f) {
  unsigned u = __builtin_bit_cast(unsigned, f);
  u += 0x7fffu + ((u >> 16) & 1u);
  return (unsigned short)(u >> 16);
}
DEVI unsigned pk2(float lo, float hi) {
  return (unsigned)f2bf(lo) | ((unsigned)f2bf(hi) << 16);
}
DEVI unsigned cvtpk(float lo, float hi) {
  unsigned r;
  asm("v_cvt_pk_bf16_f32 %0, %1, %2" : "=v"(r) : "v"(lo), "v"(hi));
  return r;
}
DEVI float exp2a(float x) { return __builtin_amdgcn_exp2f(x); }

#define MFMA32 __builtin_amdgcn_mfma_f32_32x32x16_bf16
// Q pre-scaled by C = 0.125*log2(e): p = exp(S/8) = exp2(S'). Logits statically
// bounded for this problem (p <= ~e^6): no running max needed.
#define C_L2E 0.18033688011112042f

// ============ aux kernel: prep (blocks 0..255) + gram (blocks 256..383) ========
// prep: fragment-pack st K and V (bf16).
// kfp[bh][t][f=half*4+kk][lane][8]: elem j = K[c=kk*16+hi*8+j][s=t*64+half*32+ln]
// vfp: PERMUTED pack so PV B-operand equals the lane's own cvtpk(P) outputs.
// gram: Mws[gb] = 0.125 * partial(V_img K_img^T) over 512 s (gb = bh*8+chunk).
__global__ __launch_bounds__(256) void aux_kernel(
    const float* __restrict__ img, const float* __restrict__ st,
    ushortT* __restrict__ kfp, ushortT* __restrict__ vfp,
    float* __restrict__ Mws) {
  __shared__ __align__(16) char pool[32768];
  const int tid = threadIdx.x;
  const int bid = blockIdx.x;
  const int w = tid >> 6, lane = tid & 63, hi = lane >> 5, ln = lane & 31;

  if (bid < 256) {
    // ----------------------------- prep role ------------------------------
    const int bh = bid >> 4, t = bid & 15;
    const int b = bh >> 3, h = bh & 7;
    const float* kbase = st + ((size_t)(b * 1536 + 512 + h * 64)) * 1024;
    const float* vbase = st + ((size_t)(b * 1536 + 1024 + h * 64)) * 1024;
    ushortT* ko = kfp + ((size_t)bh * 16 + t) * 4096;
    ushortT* vo = vfp + ((size_t)bh * 16 + t) * 4096;

    float (*kf)[65] = (float (*)[65])pool;  // [64][65]
    {
      const int c = tid >> 2, s16 = (tid & 3) * 16;
      const float* kp = kbase + (size_t)c * 1024 + t * 64 + s16;
      f32x4 a = *(const f32x4*)kp, b4 = *(const f32x4*)(kp + 4),
            c4 = *(const f32x4*)(kp + 8), d4 = *(const f32x4*)(kp + 12);
#pragma unroll
      for (int j = 0; j < 4; ++j) {
        kf[c][s16 + j] = a[j];
        kf[c][s16 + 4 + j] = b4[j];
        kf[c][s16 + 8 + j] = c4[j];
        kf[c][s16 + 12 + j] = d4[j];
      }
    }
    // V: permuted fragment pack (i<4 -> lane-half 0, i>=4 -> lane-half 1)
#pragma unroll
    for (int rep = 0; rep < 2; ++rep) {
      const int pair = tid + rep * 256;
      const int c = pair >> 3, oct = pair & 7;
      const float* vp = vbase + (size_t)c * 1024 + t * 64 + oct * 8;
      f32x4 lo = *(const f32x4*)vp, hp = *(const f32x4*)(vp + 4);
      uint2v la, ha;
      la[0] = pk2(lo[0], lo[1]); la[1] = pk2(lo[2], lo[3]);
      ha[0] = pk2(hp[0], hp[1]); ha[1] = pk2(hp[2], hp[3]);
      const int ci = c >> 5, lnn = c & 31;
      const int ss = oct >> 2, kk2 = (oct >> 1) & 1, o1 = oct & 1;
      const int f = ss * 4 + kk2 * 2 + ci;
      *(uint2v*)(vo + ((size_t)f * 64 + lnn) * 8 + o1 * 4) = la;
      *(uint2v*)(vo + ((size_t)f * 64 + 32 + lnn) * 8 + o1 * 4) = ha;
    }
    __syncthreads();
    {
      const int kk = w;
#pragma unroll
      for (int half = 0; half < 2; ++half) {
        float v8[8];
#pragma unroll
        for (int j = 0; j < 8; ++j) v8[j] = kf[kk * 16 + hi * 8 + j][half * 32 + ln];
        U8 u;
#pragma unroll
        for (int i = 0; i < 4; ++i) u.u[i] = pk2(v8[2 * i], v8[2 * i + 1]);
        *(short8*)(ko + ((size_t)(half * 4 + kk) * 64 + lane) * 8) = u.s8;
      }
    }
  } else {
    // ----------------------------- gram role ------------------------------
    const int gb = bid - 256;  // 0..127 = 16 bh * 8 chunks(512 s)
    const int bh = gb >> 3, chunk = gb & 7;
    const int b = bh >> 3, h = bh & 7;
    const float* kbase = img + ((size_t)(b * 1536 + 512 + h * 64)) * 4096;
    const float* vbase = img + ((size_t)(b * 1536 + 1024 + h * 64)) * 4096;

    f32x16 m00 = {}, m01 = {}, m10 = {}, m11 = {};
    const int sbeg = chunk * 512 + w * 128;
    for (int s0 = sbeg; s0 < sbeg + 128; s0 += 16) {
      const int sa = s0 + hi * 8;
      short8 av[2], bk[2];
#pragma unroll
      for (int ci = 0; ci < 2; ++ci) {
        const float* vp = vbase + (size_t)(ci * 32 + ln) * 4096 + sa;
        f32x4 lo = *(const f32x4*)vp, hp = *(const f32x4*)(vp + 4);
        U8 u;
        u.u[0] = pk2(lo[0], lo[1]); u.u[1] = pk2(lo[2], lo[3]);
        u.u[2] = pk2(hp[0], hp[1]); u.u[3] = pk2(hp[2], hp[3]);
        av[ci] = u.s8;
      }
#pragma unroll
      for (int cj = 0; cj < 2; ++cj) {
        const float* kp = kbase + (size_t)(cj * 32 + ln) * 4096 + sa;
        f32x4 lo = *(const f32x4*)kp, hp = *(const f32x4*)(kp + 4);
        U8 u;
        u.u[0] = pk2(lo[0], lo[1]); u.u[1] = pk2(lo[2], lo[3]);
        u.u[2] = pk2(hp[0], hp[1]); u.u[3] = pk2(hp[2], hp[3]);
        bk[cj] = u.s8;
      }
      m00 = MFMA32(av[0], bk[0], m00, 0, 0, 0);
      m01 = MFMA32(av[0], bk[1], m01, 0, 0, 0);
      m10 = MFMA32(av[1], bk[0], m10, 0, 0, 0);
      m11 = MFMA32(av[1], bk[1], m11, 0, 0, 0);
    }

    float (*part)[64][64] = (float (*)[64][64])pool;  // [2][64][64]
    if (w < 2) {
#pragma unroll
      for (int q = 0; q < 16; ++q) {
        const int cr = (q & 3) + 8 * (q >> 2) + 4 * hi;
        part[w][cr][ln] = m00[q];
        part[w][cr][32 + ln] = m01[q];
        part[w][32 + cr][ln] = m10[q];
        part[w][32 + cr][32 + ln] = m11[q];
      }
    }
    __syncthreads();
    if (w >= 2) {
      const int pw = w - 2;
#pragma unroll
      for (int q = 0; q < 16; ++q) {
        const int cr = (q & 3) + 8 * (q >> 2) + 4 * hi;
        part[pw][cr][ln] += m00[q];
        part[pw][cr][32 + ln] += m01[q];
        part[pw][32 + cr][ln] += m10[q];
        part[pw][32 + cr][32 + ln] += m11[q];
      }
    }
    __syncthreads();
#pragma unroll
    for (int i = 0; i < 16; ++i) {
      const int e = tid + i * 256;
      const int c = e >> 6, cp = e & 63;
      Mws[(size_t)gb * 4096 + c * 64 + cp] =
          (part[0][c][cp] + part[1][c][cp]) * 0.125f;
    }
  }
}

// ============ main kernel: attn (blocks 0..511) + st2 (blocks 512..575) ========
DEVI void stage_tile(ushortT (*lds)[16][512], int buf, const ushortT* kf_all,
                     const ushortT* vf_all, int fpbase, int lane, int tile) {
#pragma unroll
  for (int j = 0; j < 4; ++j) {
    const int fp = fpbase + j;
    const ushortT* src =
        (fp < 8 ? kf_all + (size_t)tile * 4096 + (size_t)fp * 512
                : vf_all + (size_t)tile * 4096 + (size_t)(fp - 8) * 512) +
        lane * 8;
    __builtin_amdgcn_global_load_lds(
        (const __attribute__((address_space(1))) void*)src,
        (__attribute__((address_space(3))) void*)&lds[buf][fp][0], 16, 0, 0);
  }
}

DEVI void st2_body(const float* __restrict__ st, const float* __restrict__ Mws,
                   float* __restrict__ out1, int sb, int tid, char* pool) {
  const int bh = sb >> 2, tt = sb & 3;
  const int b = bh >> 3, h = bh & 7;
  const float* qbase = st + ((size_t)(b * 1536 + h * 64)) * 1024;
  float* o1 = out1 + ((size_t)(b * 512 + h * 64)) * 1024;
  char* msb = pool;  // 16 KB: Ms[64][64] XOR-swizzled rows

#pragma unroll
  for (int i = 0; i < 16; ++i) {
    const int e = tid + i * 256;
    const int c = e >> 6, cp = e & 63;
    const float* mp = Mws + (size_t)bh * 8 * 4096 + c * 64 + cp;
    float s = 0.f;
#pragma unroll
    for (int ch = 0; ch < 8; ++ch) s += mp[(size_t)ch * 4096];
    *(float*)(msb + c * 256 + ((cp * 4) ^ ((c & 7) << 5))) = s;
  }
  __syncthreads();

  const int w = tid >> 6, lane = tid & 63, hi = lane >> 5, ln = lane & 31;

  short8 aM0[4], aM1[4];
#pragma unroll
  for (int k = 0; k < 4; ++k) {
#pragma unroll
    for (int ci = 0; ci < 2; ++ci) {
      const int row = ci * 32 + ln;
      const int bo = k * 64 + hi * 32;
      const char* rp = msb + row * 256;
      const int swz = (row & 7) << 5;
      f32x4 lo = *(const f32x4*)(rp + (bo ^ swz));
      f32x4 hp = *(const f32x4*)(rp + ((bo + 16) ^ swz));
      U8 u;
      u.u[0] = pk2(lo[0], lo[1]); u.u[1] = pk2(lo[2], lo[3]);
      u.u[2] = pk2(hp[0], hp[1]); u.u[3] = pk2(hp[2], hp[3]);
      if (ci) aM1[k] = u.s8; else aM0[k] = u.s8;
    }
  }

#pragma unroll
  for (int nt = 0; nt < 2; ++nt) {
    const int t = tt * 256 + w * 64 + nt * 32 + ln;
    short8 bq[4];
#pragma unroll
    for (int k = 0; k < 4; ++k) {
      const float* qp = qbase + (size_t)(k * 16 + hi * 8) * 1024 + t;
      float q8[8];
#pragma unroll
      for (int j = 0; j < 8; ++j) q8[j] = qp[(size_t)j * 1024];
      U8 u;
#pragma unroll
      for (int i = 0; i < 4; ++i) u.u[i] = pk2(q8[2 * i], q8[2 * i + 1]);
      bq[k] = u.s8;
    }
    f32x16 a0 = {}, a1 = {};
#pragma unroll
    for (int k = 0; k < 4; ++k) {
      a0 = MFMA32(aM0[k], bq[k], a0, 0, 0, 0);
      a1 = MFMA32(aM1[k], bq[k], a1, 0, 0, 0);
    }
#pragma unroll
    for (int q = 0; q < 16; ++q) {
      const int cr = (q & 3) + 8 * (q >> 2) + 4 * hi;
      o1[(size_t)cr * 1024 + t] = a0[q];
      o1[(size_t)(cr + 32) * 1024 + t] = a1[q];
    }
  }
}

template <bool WITH_ST2>
__global__ __launch_bounds__(256, 2) void main_kernel(
    const float* __restrict__ img, const ushortT* __restrict__ kfp,
    const ushortT* __restrict__ vfp, const float* __restrict__ st,
    const float* __restrict__ Mws, float* __restrict__ out0,
    float* __restrict__ out1) {
  __shared__ __align__(16) char pool[65536];  // 4 x 16 KB tile buffers
  const int tid = threadIdx.x;
  const int bid = blockIdx.x;

  if (WITH_ST2 && bid >= 512) {
    st2_body(st, Mws, out1, bid - 512, tid, pool);
    return;
  }

  // ============ attn role: attn_i = softmax(img_q^T st_k) * st_v ============
  // 16 bh * 32 t-blocks(128t); 4 t-waves; 16 steps over 1024 s.
  // 4-buffer LDS pipeline: stage(i+3) at top of step i; per-step sync is
  // s_waitcnt vmcnt(8) + raw s_barrier (stages i+3,i+2 stay in flight; i+1
  // forced complete). Buffer (i+3)&3 was last read in step i-1, and the
  // step-(i-1) barrier precedes this write issue -> WAR safe.
  const int w = tid >> 6, lane = tid & 63, hi = lane >> 5, ln = lane & 31;
  const int bh = bid >> 5, tb = bid & 31;
  const int b = bh >> 3, h = bh & 7;
  const float* qbase = img + ((size_t)(b * 1536 + h * 64)) * 4096;
  float* obase = out0 + ((size_t)(b * 512 + h * 64)) * 4096;

  const int fpbase = w * 4;
  const int tcol = tb * 128 + w * 32 + ln;

  ushortT (*lds)[16][512] = (ushortT (*)[16][512])pool;  // [4][16][512]
  const ushortT* kf_all = kfp + (size_t)bh * 16 * 4096;
  const ushortT* vf_all = vfp + (size_t)bh * 16 * 4096;

  stage_tile(lds, 0, kf_all, vf_all, fpbase, lane, 0);
  stage_tile(lds, 1, kf_all, vf_all, fpbase, lane, 1);
  stage_tile(lds, 2, kf_all, vf_all, fpbase, lane, 2);

  // Q fragments, pre-scaled by C_L2E: elem j = C*Q[k*16+hi*8+j][tcol]
  short8 qf[4];
#pragma unroll
  for (int k = 0; k < 4; ++k) {
    const float* qp = qbase + (size_t)(k * 16 + hi * 8) * 4096 + tcol;
    float q8[8];
#pragma unroll
    for (int j = 0; j < 8; ++j) q8[j] = qp[(size_t)j * 4096] * C_L2E;
    U8 u;
#pragma unroll
    for (int i = 0; i < 4; ++i) u.u[i] = pk2(q8[2 * i], q8[2 * i + 1]);
    qf[k] = u.s8;
  }

  f32x16 o0 = {}, o1 = {};
  float la0 = 0.f, la1 = 0.f, la2 = 0.f, la3 = 0.f;

  __syncthreads();  // prologue: single full drain (tiles 0..2 staged)

  for (int i = 0; i < 16; ++i) {
    // stage tile i+3 first: maximize in-flight distance (~3 steps)
    if (i + 3 < 16)
      stage_tile(lds, (i + 3) & 3, kf_all, vf_all, fpbase, lane, i + 3);

    const ushortT(*L)[512] = lds[i & 3];

    // QK^T: two independent 4-deep MFMA chains, interleaved
    f32x16 sc0 = {}, sc1 = {};
    {
      short8 kfr[8];
#pragma unroll
      for (int f = 0; f < 8; ++f) kfr[f] = *(const short8*)&L[f][lane * 8];
      __builtin_amdgcn_s_setprio(1);
      sc0 = MFMA32(kfr[0], qf[0], sc0, 0, 0, 0);
      sc1 = MFMA32(kfr[4], qf[0], sc1, 0, 0, 0);
      sc0 = MFMA32(kfr[1], qf[1], sc0, 0, 0, 0);
      sc1 = MFMA32(kfr[5], qf[1], sc1, 0, 0, 0);
      sc0 = MFMA32(kfr[2], qf[2], sc0, 0, 0, 0);
      sc1 = MFMA32(kfr[6], qf[2], sc1, 0, 0, 0);
      sc0 = MFMA32(kfr[3], qf[3], sc0, 0, 0, 0);
      sc1 = MFMA32(kfr[7], qf[3], sc1, 0, 0, 0);
      __builtin_amdgcn_s_setprio(0);
    }

    // p = exp2(S'); l accumulated across steps (no max, no rescale)
#pragma unroll
    for (int q = 0; q < 16; q += 4) {
      float p0 = exp2a(sc0[q]);
      float p1 = exp2a(sc0[q + 1]);
      float p2 = exp2a(sc0[q + 2]);
      float p3 = exp2a(sc0[q + 3]);
      sc0[q] = p0; sc0[q + 1] = p1; sc0[q + 2] = p2; sc0[q + 3] = p3;
      la0 += p0; la1 += p1; la2 += p2; la3 += p3;
    }
#pragma unroll
    for (int q = 0; q < 16; q += 4) {
      float p0 = exp2a(sc1[q]);
      float p1 = exp2a(sc1[q + 1]);
      float p2 = exp2a(sc1[q + 2]);
      float p3 = exp2a(sc1[q + 3]);
      sc1[q] = p0; sc1[q + 1] = p1; sc1[q + 2] = p2; sc1[q + 3] = p3;
      la0 += p0; la1 += p1; la2 += p2; la3 += p3;
    }

    // PV: B-frags are the lane's own cvtpk outputs (permuted V pack)
#pragma unroll
    for (int ss = 0; ss < 2; ++ss) {
      const f32x16& sc = ss ? sc1 : sc0;
      U8 B0, B1;
      B0.u[0] = cvtpk(sc[0], sc[1]);   B0.u[1] = cvtpk(sc[2], sc[3]);
      B0.u[2] = cvtpk(sc[4], sc[5]);   B0.u[3] = cvtpk(sc[6], sc[7]);
      B1.u[0] = cvtpk(sc[8], sc[9]);   B1.u[1] = cvtpk(sc[10], sc[11]);
      B1.u[2] = cvtpk(sc[12], sc[13]); B1.u[3] = cvtpk(sc[14], sc[15]);
      short8 v00 = *(const short8*)&L[8 + ss * 4 + 0][lane * 8];
      short8 v01 = *(const short8*)&L[8 + ss * 4 + 1][lane * 8];
      short8 v10 = *(const short8*)&L[8 + ss * 4 + 2][lane * 8];
      short8 v11 = *(const short8*)&L[8 + ss * 4 + 3][lane * 8];
      __builtin_amdgcn_s_setprio(1);
      o0 = MFMA32(v00, B0.s8, o0, 0, 0, 0);
      o1 = MFMA32(v01, B0.s8, o1, 0, 0, 0);
      o0 = MFMA32(v10, B1.s8, o0, 0, 0, 0);
      o1 = MFMA32(v11, B1.s8, o1, 0, 0, 0);
      __builtin_amdgcn_s_setprio(0);
    }

    if (i + 1 < 16) {
      // counted sync: stage(i+1) forced complete, stages i+2/i+3 stay in flight
      asm volatile("s_waitcnt vmcnt(8)" ::: "memory");
      __builtin_amdgcn_s_barrier();
      __builtin_amdgcn_sched_barrier(0);
    }
  }

  float l = (la0 + la1) + (la2 + la3);
  l += __shfl_xor(l, 32);
  const float linv = 1.0f / l;
#pragma unroll
  for (int q = 0; q < 16; ++q) {
    const int c = (q & 3) + 8 * (q >> 2) + 4 * hi;
    obase[(size_t)c * 4096 + tcol] = o0[q] * linv;
    obase[(size_t)(c + 32) * 4096 + tcol] = o1[q] * linv;
  }
}

// standalone st2 for the small-ws fallback (runs after main; out1 reuse safe)
__global__ __launch_bounds__(256) void st2_kernel(
    const float* __restrict__ st, const float* __restrict__ Mws,
    float* __restrict__ out1) {
  __shared__ __align__(16) char pool[16384];
  st2_body(st, Mws, out1, blockIdx.x, threadIdx.x, pool);
}

extern "C" void kernel_launch(void* const* d_in, const int* in_sizes, int n_in,
                              void* d_out, int out_size, void* d_ws, size_t ws_size,
                              hipStream_t stream) {
  const float* img = (const float*)d_in[0];
  const float* st = (const float*)d_in[1];
  float* out0 = (float*)d_out;
  float* out1 = out0 + (size_t)2 * 512 * 4096;
  char* ws = (char*)d_ws;
  const size_t MB = 1u << 20;

  ushortT* kfp;
  ushortT* vfp;
  float* Ms;
  bool fits = ws_size >= 6 * MB;
  if (fits) {
    kfp = (ushortT*)ws; vfp = (ushortT*)(ws + 2 * MB); Ms = (float*)(ws + 4 * MB);
  } else {
    // stash packed K/V in out1's region (4 MB); st2 runs after main and
    // overwrites it last (kernel order on the stream guarantees safety)
    kfp = (ushortT*)out1; vfp = (ushortT*)((char*)out1 + 2 * MB);
    Ms = (float*)ws;  // needs 2 MB
  }

  hipLaunchKernelGGL(aux_kernel, dim3(384), dim3(256), 0, stream, img, st, kfp,
                     vfp, Ms);
  if (fits) {
    hipLaunchKernelGGL((main_kernel<true>), dim3(576), dim3(256), 0, stream, img,
                       kfp, vfp, st, Ms, out0, out1);
  } else {
    hipLaunchKernelGGL((main_kernel<false>), dim3(512), dim3(256), 0, stream, img,
                       kfp, vfp, st, Ms, out0, out1);
    hipLaunchKernelGGL(st2_kernel, dim3(64), dim3(256), 0, stream, st, Ms, out1);
  }
}

// Round 11
// 45.356 us; speedup vs baseline: 1.0054x; 1.0054x over previous
//
#include <hip/hip_runtime.h>
#include <hip/hip_bf16.h>
#include <stdint.h>

#define DEVI __device__ __forceinline__

typedef __attribute__((ext_vector_type(8))) short short8;
typedef __attribute__((ext_vector_type(16))) float f32x16;
typedef __attribute__((ext_vector_type(4))) float f32x4;
typedef __attribute__((ext_vector_type(2))) unsigned int uint2v;
typedef unsigned short ushortT;

union U8 { short8 s8; unsigned u[4]; };

DEVI unsigned short f2bf(float f) {
  unsigned u = __builtin_bit_cast(unsigned, f);
  u += 0x7fffu + ((u >> 16) & 1u);
  return (unsigned short)(u >> 16);
}
DEVI unsigned pk2(float lo, float hi) {
  return (unsigned)f2bf(lo) | ((unsigned)f2bf(hi) << 16);
}
DEVI unsigned cvtpk(float lo, float hi) {
  unsigned r;
  asm("v_cvt_pk_bf16_f32 %0, %1, %2" : "=v"(r) : "v"(lo), "v"(hi));
  return r;
}
DEVI float exp2a(float x) { return __builtin_amdgcn_exp2f(x); }

#define MFMA32 __builtin_amdgcn_mfma_f32_32x32x16_bf16
// Q pre-scaled by C = 0.125*log2(e): p = exp(S/8) = exp2(S'). Logits statically
// bounded for this problem (p <= ~e^6): no running max needed.
#define C_L2E 0.18033688011112042f

// ============ aux kernel: prep (blocks 0..255) + gram (blocks 256..383) ========
__global__ __launch_bounds__(256) void aux_kernel(
    const float* __restrict__ img, const float* __restrict__ st,
    ushortT* __restrict__ kfp, ushortT* __restrict__ vfp,
    float* __restrict__ Mws) {
  __shared__ __align__(16) char pool[32768];
  const int tid = threadIdx.x;
  const int bid = blockIdx.x;
  const int w = tid >> 6, lane = tid & 63, hi = lane >> 5, ln = lane & 31;

  if (bid < 256) {
    // ----------------------------- prep role ------------------------------
    const int bh = bid >> 4, t = bid & 15;
    const int b = bh >> 3, h = bh & 7;
    const float* kbase = st + ((size_t)(b * 1536 + 512 + h * 64)) * 1024;
    const float* vbase = st + ((size_t)(b * 1536 + 1024 + h * 64)) * 1024;
    ushortT* ko = kfp + ((size_t)bh * 16 + t) * 4096;
    ushortT* vo = vfp + ((size_t)bh * 16 + t) * 4096;

    float (*kf)[65] = (float (*)[65])pool;  // [64][65]
    {
      const int c = tid >> 2, s16 = (tid & 3) * 16;
      const float* kp = kbase + (size_t)c * 1024 + t * 64 + s16;
      f32x4 a = *(const f32x4*)kp, b4 = *(const f32x4*)(kp + 4),
            c4 = *(const f32x4*)(kp + 8), d4 = *(const f32x4*)(kp + 12);
#pragma unroll
      for (int j = 0; j < 4; ++j) {
        kf[c][s16 + j] = a[j];
        kf[c][s16 + 4 + j] = b4[j];
        kf[c][s16 + 8 + j] = c4[j];
        kf[c][s16 + 12 + j] = d4[j];
      }
    }
    // V: permuted fragment pack (i<4 -> lane-half 0, i>=4 -> lane-half 1)
#pragma unroll
    for (int rep = 0; rep < 2; ++rep) {
      const int pair = tid + rep * 256;
      const int c = pair >> 3, oct = pair & 7;
      const float* vp = vbase + (size_t)c * 1024 + t * 64 + oct * 8;
      f32x4 lo = *(const f32x4*)vp, hp = *(const f32x4*)(vp + 4);
      uint2v la, ha;
      la[0] = pk2(lo[0], lo[1]); la[1] = pk2(lo[2], lo[3]);
      ha[0] = pk2(hp[0], hp[1]); ha[1] = pk2(hp[2], hp[3]);
      const int ci = c >> 5, lnn = c & 31;
      const int ss = oct >> 2, kk2 = (oct >> 1) & 1, o1 = oct & 1;
      const int f = ss * 4 + kk2 * 2 + ci;
      *(uint2v*)(vo + ((size_t)f * 64 + lnn) * 8 + o1 * 4) = la;
      *(uint2v*)(vo + ((size_t)f * 64 + 32 + lnn) * 8 + o1 * 4) = ha;
    }
    __syncthreads();
    {
      const int kk = w;
#pragma unroll
      for (int half = 0; half < 2; ++half) {
        float v8[8];
#pragma unroll
        for (int j = 0; j < 8; ++j) v8[j] = kf[kk * 16 + hi * 8 + j][half * 32 + ln];
        U8 u;
#pragma unroll
        for (int i = 0; i < 4; ++i) u.u[i] = pk2(v8[2 * i], v8[2 * i + 1]);
        *(short8*)(ko + ((size_t)(half * 4 + kk) * 64 + lane) * 8) = u.s8;
      }
    }
  } else {
    // ----------------------------- gram role ------------------------------
    const int gb = bid - 256;  // 0..127 = 16 bh * 8 chunks(512 s)
    const int bh = gb >> 3, chunk = gb & 7;
    const int b = bh >> 3, h = bh & 7;
    const float* kbase = img + ((size_t)(b * 1536 + 512 + h * 64)) * 4096;
    const float* vbase = img + ((size_t)(b * 1536 + 1024 + h * 64)) * 4096;

    f32x16 m00 = {}, m01 = {}, m10 = {}, m11 = {};
    const int sbeg = chunk * 512 + w * 128;
    for (int s0 = sbeg; s0 < sbeg + 128; s0 += 16) {
      const int sa = s0 + hi * 8;
      short8 av[2], bk[2];
#pragma unroll
      for (int ci = 0; ci < 2; ++ci) {
        const float* vp = vbase + (size_t)(ci * 32 + ln) * 4096 + sa;
        f32x4 lo = *(const f32x4*)vp, hp = *(const f32x4*)(vp + 4);
        U8 u;
        u.u[0] = pk2(lo[0], lo[1]); u.u[1] = pk2(lo[2], lo[3]);
        u.u[2] = pk2(hp[0], hp[1]); u.u[3] = pk2(hp[2], hp[3]);
        av[ci] = u.s8;
      }
#pragma unroll
      for (int cj = 0; cj < 2; ++cj) {
        const float* kp = kbase + (size_t)(cj * 32 + ln) * 4096 + sa;
        f32x4 lo = *(const f32x4*)kp, hp = *(const f32x4*)(kp + 4);
        U8 u;
        u.u[0] = pk2(lo[0], lo[1]); u.u[1] = pk2(lo[2], lo[3]);
        u.u[2] = pk2(hp[0], hp[1]); u.u[3] = pk2(hp[2], hp[3]);
        bk[cj] = u.s8;
      }
      m00 = MFMA32(av[0], bk[0], m00, 0, 0, 0);
      m01 = MFMA32(av[0], bk[1], m01, 0, 0, 0);
      m10 = MFMA32(av[1], bk[0], m10, 0, 0, 0);
      m11 = MFMA32(av[1], bk[1], m11, 0, 0, 0);
    }

    float (*part)[64][64] = (float (*)[64][64])pool;  // [2][64][64]
    if (w < 2) {
#pragma unroll
      for (int q = 0; q < 16; ++q) {
        const int cr = (q & 3) + 8 * (q >> 2) + 4 * hi;
        part[w][cr][ln] = m00[q];
        part[w][cr][32 + ln] = m01[q];
        part[w][32 + cr][ln] = m10[q];
        part[w][32 + cr][32 + ln] = m11[q];
      }
    }
    __syncthreads();
    if (w >= 2) {
      const int pw = w - 2;
#pragma unroll
      for (int q = 0; q < 16; ++q) {
        const int cr = (q & 3) + 8 * (q >> 2) + 4 * hi;
        part[pw][cr][ln] += m00[q];
        part[pw][cr][32 + ln] += m01[q];
        part[pw][32 + cr][ln] += m10[q];
        part[pw][32 + cr][32 + ln] += m11[q];
      }
    }
    __syncthreads();
#pragma unroll
    for (int i = 0; i < 16; ++i) {
      const int e = tid + i * 256;
      const int c = e >> 6, cp = e & 63;
      Mws[(size_t)gb * 4096 + c * 64 + cp] =
          (part[0][c][cp] + part[1][c][cp]) * 0.125f;
    }
  }
}

// ============ main kernel: attn (blocks 0..511) + st2 (blocks 512..575) ========
DEVI void stage_tile(ushortT (*lds)[16][512], int buf, const ushortT* kf_all,
                     const ushortT* vf_all, int fpbase, int lane, int tile) {
#pragma unroll
  for (int j = 0; j < 4; ++j) {
    const int fp = fpbase + j;
    const ushortT* src =
        (fp < 8 ? kf_all + (size_t)tile * 4096 + (size_t)fp * 512
                : vf_all + (size_t)tile * 4096 + (size_t)(fp - 8) * 512) +
        lane * 8;
    __builtin_amdgcn_global_load_lds(
        (const __attribute__((address_space(1))) void*)src,
        (__attribute__((address_space(3))) void*)&lds[buf][fp][0], 16, 0, 0);
  }
}

DEVI void st2_body(const float* __restrict__ st, const float* __restrict__ Mws,
                   float* __restrict__ out1, int sb, int tid, char* pool) {
  const int bh = sb >> 2, tt = sb & 3;
  const int b = bh >> 3, h = bh & 7;
  const float* qbase = st + ((size_t)(b * 1536 + h * 64)) * 1024;
  float* o1 = out1 + ((size_t)(b * 512 + h * 64)) * 1024;
  char* msb = pool;  // 16 KB: Ms[64][64] XOR-swizzled rows

#pragma unroll
  for (int i = 0; i < 16; ++i) {
    const int e = tid + i * 256;
    const int c = e >> 6, cp = e & 63;
    const float* mp = Mws + (size_t)bh * 8 * 4096 + c * 64 + cp;
    float s = 0.f;
#pragma unroll
    for (int ch = 0; ch < 8; ++ch) s += mp[(size_t)ch * 4096];
    *(float*)(msb + c * 256 + ((cp * 4) ^ ((c & 7) << 5))) = s;
  }
  __syncthreads();

  const int w = tid >> 6, lane = tid & 63, hi = lane >> 5, ln = lane & 31;

  short8 aM0[4], aM1[4];
#pragma unroll
  for (int k = 0; k < 4; ++k) {
#pragma unroll
    for (int ci = 0; ci < 2; ++ci) {
      const int row = ci * 32 + ln;
      const int bo = k * 64 + hi * 32;
      const char* rp = msb + row * 256;
      const int swz = (row & 7) << 5;
      f32x4 lo = *(const f32x4*)(rp + (bo ^ swz));
      f32x4 hp = *(const f32x4*)(rp + ((bo + 16) ^ swz));
      U8 u;
      u.u[0] = pk2(lo[0], lo[1]); u.u[1] = pk2(lo[2], lo[3]);
      u.u[2] = pk2(hp[0], hp[1]); u.u[3] = pk2(hp[2], hp[3]);
      if (ci) aM1[k] = u.s8; else aM0[k] = u.s8;
    }
  }

#pragma unroll
  for (int nt = 0; nt < 2; ++nt) {
    const int t = tt * 256 + w * 64 + nt * 32 + ln;
    short8 bq[4];
#pragma unroll
    for (int k = 0; k < 4; ++k) {
      const float* qp = qbase + (size_t)(k * 16 + hi * 8) * 1024 + t;
      float q8[8];
#pragma unroll
      for (int j = 0; j < 8; ++j) q8[j] = qp[(size_t)j * 1024];
      U8 u;
#pragma unroll
      for (int i = 0; i < 4; ++i) u.u[i] = pk2(q8[2 * i], q8[2 * i + 1]);
      bq[k] = u.s8;
    }
    f32x16 a0 = {}, a1 = {};
#pragma unroll
    for (int k = 0; k < 4; ++k) {
      a0 = MFMA32(aM0[k], bq[k], a0, 0, 0, 0);
      a1 = MFMA32(aM1[k], bq[k], a1, 0, 0, 0);
    }
#pragma unroll
    for (int q = 0; q < 16; ++q) {
      const int cr = (q & 3) + 8 * (q >> 2) + 4 * hi;
      o1[(size_t)cr * 1024 + t] = a0[q];
      o1[(size_t)(cr + 32) * 1024 + t] = a1[q];
    }
  }
}

// One pipelined step: consumes P(i) (in cA, computed last step), produces
// scores for tile i+1 (into cB), and does PV(i). Tile readability invariant:
// vmcnt(4) at end of step j forces stage(j+1) complete -> tile j readable from
// step j-1. Step i reads tile i (V) and tile i+1 (K): both legal.
DEVI void step_pipe(ushortT (*lds)[16][512], const ushortT* kf_all,
                    const ushortT* vf_all, int fpbase, int lane, int i,
                    const short8 (&qf)[4], f32x16& cA0, f32x16& cA1,
                    f32x16& cB0, f32x16& cB1, f32x16& o0, f32x16& o1,
                    float& la0, float& la1, float& la2, float& la3) {
  // stage tile i+3 (writes buffer (i+3)&3, last read in step i-1 -> WAR safe)
  if (i + 3 < 16)
    stage_tile(lds, (i + 3) & 3, kf_all, vf_all, fpbase, lane, i + 3);

  const ushortT(*Lc)[512] = lds[i & 3];
  const ushortT(*Ln)[512] = lds[(i + 1) & 3];

  // early ds_reads: V(i) for PV, K(i+1) for next scores (latency hides
  // under the softmax VALU below)
  short8 vf[8], kn[8];
#pragma unroll
  for (int f = 0; f < 8; ++f) vf[f] = *(const short8*)&Lc[8 + f][lane * 8];
#pragma unroll
  for (int f = 0; f < 8; ++f) kn[f] = *(const short8*)&Ln[f][lane * 8];

  // softmax numerator on cA: p = exp2(S'); l accumulated
#pragma unroll
  for (int q = 0; q < 16; q += 4) {
    float p0 = exp2a(cA0[q]);
    float p1 = exp2a(cA0[q + 1]);
    float p2 = exp2a(cA0[q + 2]);
    float p3 = exp2a(cA0[q + 3]);
    cA0[q] = p0; cA0[q + 1] = p1; cA0[q + 2] = p2; cA0[q + 3] = p3;
    la0 += p0; la1 += p1; la2 += p2; la3 += p3;
  }
#pragma unroll
  for (int q = 0; q < 16; q += 4) {
    float p0 = exp2a(cA1[q]);
    float p1 = exp2a(cA1[q + 1]);
    float p2 = exp2a(cA1[q + 2]);
    float p3 = exp2a(cA1[q + 3]);
    cA1[q] = p0; cA1[q + 1] = p1; cA1[q + 2] = p2; cA1[q + 3] = p3;
    la0 += p0; la1 += p1; la2 += p2; la3 += p3;
  }

  // QK^T for tile i+1 (independent of this step's softmax/PV chain)
  cB0 = (f32x16){};
  cB1 = (f32x16){};
  __builtin_amdgcn_s_setprio(1);
  cB0 = MFMA32(kn[0], qf[0], cB0, 0, 0, 0);
  cB1 = MFMA32(kn[4], qf[0], cB1, 0, 0, 0);
  cB0 = MFMA32(kn[1], qf[1], cB0, 0, 0, 0);
  cB1 = MFMA32(kn[5], qf[1], cB1, 0, 0, 0);
  cB0 = MFMA32(kn[2], qf[2], cB0, 0, 0, 0);
  cB1 = MFMA32(kn[6], qf[2], cB1, 0, 0, 0);
  cB0 = MFMA32(kn[3], qf[3], cB0, 0, 0, 0);
  cB1 = MFMA32(kn[7], qf[3], cB1, 0, 0, 0);
  __builtin_amdgcn_s_setprio(0);

  // PV(i): B-frags are the lane's own cvtpk outputs (permuted V pack)
#pragma unroll
  for (int ss = 0; ss < 2; ++ss) {
    const f32x16& sc = ss ? cA1 : cA0;
    U8 B0, B1;
    B0.u[0] = cvtpk(sc[0], sc[1]);   B0.u[1] = cvtpk(sc[2], sc[3]);
    B0.u[2] = cvtpk(sc[4], sc[5]);   B0.u[3] = cvtpk(sc[6], sc[7]);
    B1.u[0] = cvtpk(sc[8], sc[9]);   B1.u[1] = cvtpk(sc[10], sc[11]);
    B1.u[2] = cvtpk(sc[12], sc[13]); B1.u[3] = cvtpk(sc[14], sc[15]);
    __builtin_amdgcn_s_setprio(1);
    o0 = MFMA32(vf[ss * 4 + 0], B0.s8, o0, 0, 0, 0);
    o1 = MFMA32(vf[ss * 4 + 1], B0.s8, o1, 0, 0, 0);
    o0 = MFMA32(vf[ss * 4 + 2], B1.s8, o0, 0, 0, 0);
    o1 = MFMA32(vf[ss * 4 + 3], B1.s8, o1, 0, 0, 0);
    __builtin_amdgcn_s_setprio(0);
  }

  if (i + 1 < 16) {
    // counted sync: leave newest 4 (stage i+3) in flight; forces stage i+2
    asm volatile("s_waitcnt vmcnt(4)" ::: "memory");
    __builtin_amdgcn_s_barrier();
    __builtin_amdgcn_sched_barrier(0);
  }
}

template <bool WITH_ST2>
__global__ __launch_bounds__(256, 2) void main_kernel(
    const float* __restrict__ img, const ushortT* __restrict__ kfp,
    const ushortT* __restrict__ vfp, const float* __restrict__ st,
    const float* __restrict__ Mws, float* __restrict__ out0,
    float* __restrict__ out1) {
  __shared__ __align__(16) char pool[65536];  // 4 x 16 KB tile buffers
  const int tid = threadIdx.x;
  const int bid = blockIdx.x;

  if (WITH_ST2 && bid >= 512) {
    st2_body(st, Mws, out1, bid - 512, tid, pool);
    return;
  }

  // ============ attn role: attn_i = softmax(img_q^T st_k) * st_v ============
  const int w = tid >> 6, lane = tid & 63, hi = lane >> 5, ln = lane & 31;
  const int bh = bid >> 5, tb = bid & 31;
  const int b = bh >> 3, h = bh & 7;
  const float* qbase = img + ((size_t)(b * 1536 + h * 64)) * 4096;
  float* obase = out0 + ((size_t)(b * 512 + h * 64)) * 4096;

  const int fpbase = w * 4;
  const int tcol = tb * 128 + w * 32 + ln;

  ushortT (*lds)[16][512] = (ushortT (*)[16][512])pool;  // [4][16][512]
  const ushortT* kf_all = kfp + (size_t)bh * 16 * 4096;
  const ushortT* vf_all = vfp + (size_t)bh * 16 * 4096;

  stage_tile(lds, 0, kf_all, vf_all, fpbase, lane, 0);
  stage_tile(lds, 1, kf_all, vf_all, fpbase, lane, 1);
  stage_tile(lds, 2, kf_all, vf_all, fpbase, lane, 2);

  // Q fragments, pre-scaled by C_L2E: elem j = C*Q[k*16+hi*8+j][tcol]
  short8 qf[4];
#pragma unroll
  for (int k = 0; k < 4; ++k) {
    const float* qp = qbase + (size_t)(k * 16 + hi * 8) * 4096 + tcol;
    float q8[8];
#pragma unroll
    for (int j = 0; j < 8; ++j) q8[j] = qp[(size_t)j * 4096] * C_L2E;
    U8 u;
#pragma unroll
    for (int i = 0; i < 4; ++i) u.u[i] = pk2(q8[2 * i], q8[2 * i + 1]);
    qf[k] = u.s8;
  }

  f32x16 o0 = {}, o1 = {};
  float la0 = 0.f, la1 = 0.f, la2 = 0.f, la3 = 0.f;

  __syncthreads();  // prologue: single full drain (tiles 0..2 staged)

  // prologue QK(0) -> sA
  f32x16 sA0 = {}, sA1 = {}, sB0 = {}, sB1 = {};
  {
    short8 k0[8];
#pragma unroll
    for (int f = 0; f < 8; ++f) k0[f] = *(const short8*)&lds[0][f][lane * 8];
    __builtin_amdgcn_s_setprio(1);
    sA0 = MFMA32(k0[0], qf[0], sA0, 0, 0, 0);
    sA1 = MFMA32(k0[4], qf[0], sA1, 0, 0, 0);
    sA0 = MFMA32(k0[1], qf[1], sA0, 0, 0, 0);
    sA1 = MFMA32(k0[5], qf[1], sA1, 0, 0, 0);
    sA0 = MFMA32(k0[2], qf[2], sA0, 0, 0, 0);
    sA1 = MFMA32(k0[6], qf[2], sA1, 0, 0, 0);
    sA0 = MFMA32(k0[3], qf[3], sA0, 0, 0, 0);
    sA1 = MFMA32(k0[7], qf[3], sA1, 0, 0, 0);
    __builtin_amdgcn_s_setprio(0);
  }

  for (int ii = 0; ii < 16; ii += 2) {
    step_pipe(lds, kf_all, vf_all, fpbase, lane, ii, qf, sA0, sA1, sB0, sB1,
              o0, o1, la0, la1, la2, la3);
    step_pipe(lds, kf_all, vf_all, fpbase, lane, ii + 1, qf, sB0, sB1, sA0, sA1,
              o0, o1, la0, la1, la2, la3);
  }

  float l = (la0 + la1) + (la2 + la3);
  l += __shfl_xor(l, 32);
  const float linv = 1.0f / l;
#pragma unroll
  for (int q = 0; q < 16; ++q) {
    const int c = (q & 3) + 8 * (q >> 2) + 4 * hi;
    obase[(size_t)c * 4096 + tcol] = o0[q] * linv;
    obase[(size_t)(c + 32) * 4096 + tcol] = o1[q] * linv;
  }
}

// standalone st2 for the small-ws fallback (runs after main; out1 reuse safe)
__global__ __launch_bounds__(256) void st2_kernel(
    const float* __restrict__ st, const float* __restrict__ Mws,
    float* __restrict__ out1) {
  __shared__ __align__(16) char pool[16384];
  st2_body(st, Mws, out1, blockIdx.x, threadIdx.x, pool);
}

extern "C" void kernel_launch(void* const* d_in, const int* in_sizes, int n_in,
                              void* d_out, int out_size, void* d_ws, size_t ws_size,
                              hipStream_t stream) {
  const float* img = (const float*)d_in[0];
  const float* st = (const float*)d_in[1];
  float* out0 = (float*)d_out;
  float* out1 = out0 + (size_t)2 * 512 * 4096;
  char* ws = (char*)d_ws;
  const size_t MB = 1u << 20;

  ushortT* kfp;
  ushortT* vfp;
  float* Ms;
  bool fits = ws_size >= 6 * MB;
  if (fits) {
    kfp = (ushortT*)ws; vfp = (ushortT*)(ws + 2 * MB); Ms = (float*)(ws + 4 * MB);
  } else {
    // stash packed K/V in out1's region (4 MB); st2 runs after main and
    // overwrites it last (kernel order on the stream guarantees safety)
    kfp = (ushortT*)out1; vfp = (ushortT*)((char*)out1 + 2 * MB);
    Ms = (float*)ws;  // needs 2 MB
  }

  hipLaunchKernelGGL(aux_kernel, dim3(384), dim3(256), 0, stream, img, st, kfp,
                     vfp, Ms);
  if (fits) {
    hipLaunchKernelGGL((main_kernel<true>), dim3(576), dim3(256), 0, stream, img,
                       kfp, vfp, st, Ms, out0, out1);
  } else {
    hipLaunchKernelGGL((main_kernel<false>), dim3(512), dim3(256), 0, stream, img,
                       kfp, vfp, st, Ms, out0, out1);
    hipLaunchKernelGGL(st2_kernel, dim3(64), dim3(256), 0, stream, st, Ms, out1);
  }
}